// Round 1
// baseline (84.261 us; speedup 1.0000x reference)
//
#include <hip/hip_runtime.h>
#include <math.h>

#define Bn 128
#define Dn 1024
#define Cn 1000
#define Cpad 1024
#define GAMMA 10.0f
#define EPSv 1e-6f

#define DCH 16            // split-K slices (was 32): halves partial traffic
#define DSPAN (Dn / DCH)  // 64
#define BM 4              // batch rows per block (was 8): NBG=32 keeps grid at 512
#define NBG (Bn / BM)     // 32

// ws layout (floats):
//   lg  [DCH][Bn][Cpad]   partial logits  Σ_d A[b,d] W[d,c]      (8.4 MB)
//   dt  [DCH][Bn][Cpad]   partial dots    Σ_d W[d,t_b] W[d,c]    (8.4 MB)
//   nrm [DCH][Cpad]       partial norms   Σ_d W[d,c]^2           (64 KB)
//   vmax[Bn]              per-row max violation, float bits in int (atomicMax)

// ---------------- Pass 1: split-K partials, no atomics ----------------
__global__ __launch_bounds__(256) void lm_partial(
    const float* __restrict__ A, const float* __restrict__ W,
    const int* __restrict__ tgt,
    float* __restrict__ lg, float* __restrict__ dt,
    float* __restrict__ nrm, int* __restrict__ vmax)
{
    const int tid = threadIdx.x;
    const int bg  = blockIdx.x;     // 0..31
    const int k   = blockIdx.y;     // 0..15
    if (bg == 0 && k == 0 && tid < Bn) vmax[tid] = 0;   // pass2 atomicMax target

    const int b0 = bg * BM;
    const int d0 = k * DSPAN;
    const int c0 = tid * 4;                 // 4 consecutive columns per thread
    const bool valid = (c0 < Cn);           // tid < 250
    const int c0m = valid ? c0 : 0;

    // As4[i].j = A[b0+j][d0+i] ; Wt4[i].j = W[d0+i][tgt[b0+j]]
    __shared__ float4 As4[DSPAN];
    __shared__ float4 Wt4[DSPAN];
    {
        const int i = tid & (DSPAN - 1);    // 0..63
        const int j = tid >> 6;             // 0..3 (256 = 64*4 exactly)
        ((float*)&As4[i])[j] = A[(b0 + j) * Dn + d0 + i];
        ((float*)&Wt4[i])[j] = W[(size_t)(d0 + i) * Cn + tgt[b0 + j]];
    }
    __syncthreads();

    float aL[BM][4], aD[BM][4], aN[4];
    #pragma unroll
    for (int e = 0; e < 4; ++e) {
        aN[e] = 0.f;
        #pragma unroll
        for (int j = 0; j < BM; ++j) { aL[j][e] = 0.f; aD[j][e] = 0.f; }
    }

    const float* Wp = W + (size_t)d0 * Cn + c0m;   // (d*1000+c0)%4==0 -> 16B aligned
    #pragma unroll 4
    for (int i = 0; i < DSPAN; ++i) {
        const float4 w  = *(const float4*)(Wp + (size_t)i * Cn);
        const float4 a4 = As4[i];           // uniform LDS broadcasts (b128)
        const float4 t4 = Wt4[i];
        const float wv[4] = {w.x, w.y, w.z, w.w};
        const float av[4] = {a4.x, a4.y, a4.z, a4.w};
        const float tv[4] = {t4.x, t4.y, t4.z, t4.w};
        #pragma unroll
        for (int e = 0; e < 4; ++e) {
            aN[e] = fmaf(wv[e], wv[e], aN[e]);
            #pragma unroll
            for (int j = 0; j < BM; ++j) {
                aL[j][e] = fmaf(av[j], wv[e], aL[j][e]);
                aD[j][e] = fmaf(tv[j], wv[e], aD[j][e]);
            }
        }
    }

    if (valid) {
        #pragma unroll
        for (int j = 0; j < BM; ++j) {
            const size_t off = ((size_t)(k * Bn + b0 + j)) * Cpad + c0;
            *(float4*)&lg[off] = make_float4(aL[j][0], aL[j][1], aL[j][2], aL[j][3]);
            *(float4*)&dt[off] = make_float4(aD[j][0], aD[j][1], aD[j][2], aD[j][3]);
        }
        if (bg == 0)
            *(float4*)&nrm[(size_t)k * Cpad + c0] =
                make_float4(aN[0], aN[1], aN[2], aN[3]);
    }
}

// ------- Pass 2: reduce slices, violation, per-(b, 250-col chunk) max -------
// grid (Bn, 4): 512 blocks -> full GPU; 48 coalesced scalar loads/thread.
__global__ __launch_bounds__(256) void lm_vmax(
    const float* __restrict__ lg, const float* __restrict__ dt,
    const float* __restrict__ nrm, const float* __restrict__ bias,
    const int* __restrict__ tgt, int* __restrict__ vmax)
{
    const int b   = blockIdx.x;
    const int q   = blockIdx.y;    // 0..3
    const int tid = threadIdx.x;
    const int t   = tgt[b];

    __shared__ float s_cr, s_nt;
    if (tid < DCH) {   // 16 lanes of wave 0: reduce correct logit & target norm
        float cr = lg[((size_t)(tid * Bn + b)) * Cpad + t];
        float nt = nrm[(size_t)tid * Cpad + t];
        #pragma unroll
        for (int off = DCH / 2; off; off >>= 1) {
            cr += __shfl_down(cr, off, 64);
            nt += __shfl_down(nt, off, 64);
        }
        if (tid == 0) { s_cr = cr + bias[t]; s_nt = nt; }
    }
    __syncthreads();

    float m = 0.f;
    if (tid < 250) {
        const int c = q * 250 + tid;        // 4*250 = 1000: exact cover, coalesced
        float L = 0.f, Dt = 0.f, Nr = 0.f;
        #pragma unroll
        for (int k = 0; k < DCH; ++k) {
            L  += lg[((size_t)(k * Bn + b)) * Cpad + c];
            Dt += dt[((size_t)(k * Bn + b)) * Cpad + c];
            Nr += nrm[(size_t)k * Cpad + c];
        }
        if (c != t) {
            const float dist = fmaxf(Nr + s_nt - 2.f * Dt, 0.f);
            const float dn   = sqrtf(dist + EPSv) + EPSv;
            m = fmaxf(0.f, GAMMA + (L + bias[c] - s_cr) / dn);  // relu
        }
    }

    #pragma unroll
    for (int off = 32; off; off >>= 1) m = fmaxf(m, __shfl_down(m, off, 64));
    __shared__ float sm[4];
    if ((tid & 63) == 0) sm[tid >> 6] = m;
    __syncthreads();
    if (tid == 0) {
        const float bm = fmaxf(fmaxf(sm[0], sm[1]), fmaxf(sm[2], sm[3]));
        atomicMax(vmax + b, __float_as_int(bm));   // bm >= 0: int order == float order
    }
}

// ---------------- Pass 3: mean over batch ----------------
__global__ __launch_bounds__(128) void lm_mean(
    const int* __restrict__ vmax, float* __restrict__ out)
{
    const int tid = threadIdx.x;          // 128 threads = 2 waves
    float v = __int_as_float(vmax[tid]);
    #pragma unroll
    for (int off = 32; off; off >>= 1) v += __shfl_down(v, off, 64);
    __shared__ float sw[2];
    if ((tid & 63) == 0) sw[tid >> 6] = v;
    __syncthreads();
    if (tid == 0) out[0] = (sw[0] + sw[1]) * (1.0f / (float)Bn);
}

extern "C" void kernel_launch(void* const* d_in, const int* in_sizes, int n_in,
                              void* d_out, int out_size, void* d_ws, size_t ws_size,
                              hipStream_t stream) {
    const float* A    = (const float*)d_in[0];   // [B, D]
    const float* W    = (const float*)d_in[1];   // [D, C]
    const float* bias = (const float*)d_in[2];   // [C]
    const int*   tgt  = (const int*)d_in[3];     // [B]
    float* out = (float*)d_out;

    float* lg  = (float*)d_ws;                       // [DCH][Bn][Cpad]
    float* dt  = lg + (size_t)DCH * Bn * Cpad;       // [DCH][Bn][Cpad]
    float* nrm = dt + (size_t)DCH * Bn * Cpad;       // [DCH][Cpad]
    int*   vmx = (int*)(nrm + (size_t)DCH * Cpad);   // [Bn]

    lm_partial<<<dim3(NBG, DCH), dim3(256), 0, stream>>>(A, W, tgt, lg, dt, nrm, vmx);
    lm_vmax  <<<dim3(Bn, 4),    dim3(256), 0, stream>>>(lg, dt, nrm, bias, tgt, vmx);
    lm_mean  <<<dim3(1),        dim3(128), 0, stream>>>(vmx, out);
}